// Round 1
// 173.001 us; speedup vs baseline: 1.0183x; 1.0183x over previous
//
#include <hip/hip_runtime.h>
#include <math.h>

#define NB 32
#define NN 262144
#define NG 256
#define NC 64             // chunks per batch (sort passes)
#define CH (NN/NC)        // 4096 elements per chunk
#define SC (CH/4)         // 1024 elements per wave (4 waves/block)
#define CD 64             // chunks per batch, apply pass
#define ELD (NN/CD)       // 4096 elements per apply block

// ---- Pass 1: per-(batch,chunk,WAVE,group) counts (packed u16x4) + packed u8
//      gid emission. Wave w counts exactly elements [w*1024,(w+1)*1024) so the
//      counts seed k_scatter's running counters directly (no re-histogram). ----
__global__ __launch_bounds__(256) void k_count(const int* __restrict__ vr,
                                               unsigned long long* __restrict__ wcnt16,
                                               unsigned* __restrict__ gid32){
  __shared__ unsigned sc[4][NG];
  const int t    = threadIdx.x;
  const int lane = t & 63;
  const int w    = t >> 6;
  sc[0][t] = 0u; sc[1][t] = 0u; sc[2][t] = 0u; sc[3][t] = 0u;
  __syncthreads();

  const int b = blockIdx.x / NC;
  const int c = blockIdx.x % NC;
  const size_t base = (size_t)b*NN + (size_t)c*CH;
  const int4* v4 = (const int4*)(vr + base);

#pragma unroll
  for (int i = 0; i < 4; i++){
    int idx = w*256 + i*64 + lane;        // wave-contiguous quarter, coalesced
    int4 v = v4[idx];
    atomicAdd(&sc[w][v.x], 1u);
    atomicAdd(&sc[w][v.y], 1u);
    atomicAdd(&sc[w][v.z], 1u);
    atomicAdd(&sc[w][v.w], 1u);
    gid32[(base >> 2) + idx] =
      (unsigned)v.x | ((unsigned)v.y << 8) | ((unsigned)v.z << 16) | ((unsigned)v.w << 24);
  }
  __syncthreads();

  unsigned c0 = sc[0][t], c1 = sc[1][t], c2 = sc[2][t], c3 = sc[3][t];
  const size_t cb = (size_t)b*NC + c;
  wcnt16[cb*NG + t] = (unsigned long long)c0
                    | ((unsigned long long)c1 << 16)
                    | ((unsigned long long)c2 << 32)
                    | ((unsigned long long)c3 << 48);
}

// ---- Pass 2: absolute scatter offsets per (b,chunk,group) + group base/len ----
__global__ __launch_bounds__(256) void k_offsets(const unsigned long long* __restrict__ wcnt16,
                                                 unsigned* __restrict__ off,
                                                 unsigned* __restrict__ grpbase,
                                                 unsigned* __restrict__ grplen){
  const int b = blockIdx.x;
  const int g = threadIdx.x;

  unsigned v[NC];
#pragma unroll
  for (int c = 0; c < NC; c++){
    unsigned long long x = wcnt16[(size_t)(b*NC + c)*NG + g];
    unsigned lo = (unsigned)x, hi = (unsigned)(x >> 32);
    v[c] = (lo & 0xFFFFu) + (lo >> 16) + (hi & 0xFFFFu) + (hi >> 16);
  }
  unsigned tot = 0;
#pragma unroll
  for (int c = 0; c < NC; c++) tot += v[c];

  __shared__ unsigned ss[NG];
  ss[g] = tot; __syncthreads();
  for (int d = 1; d < NG; d <<= 1){
    unsigned x = (g >= d) ? ss[g - d] : 0u;
    __syncthreads();
    ss[g] += x;
    __syncthreads();
  }
  unsigned base = ss[g] - tot;   // exclusive prefix over groups

  unsigned run = base;
#pragma unroll
  for (int c = 0; c < NC; c++){
    off[(size_t)(b*NC + c)*NG + g] = run;
    run += v[c];
  }
  grpbase[b*NG + g] = base;
  grplen [b*NG + g] = tot;
}

// ---- Pass 3: LDS-staged stable sort of each chunk + coalesced flush ----
// Per-wave seeds come precomputed from k_count (no LDS atomics, no 16-barrier
// scan). Stability: wave ranges + stripe order + ballot rank preserve global
// element order bit-exactly (the fp32 sum chain downstream depends on it).
__global__ __launch_bounds__(256) void k_scatter(const float* __restrict__ pr,
                                                 const unsigned* __restrict__ gid32,
                                                 const unsigned* __restrict__ off,
                                                 const unsigned long long* __restrict__ wcnt16,
                                                 float* __restrict__ sorted){
  __shared__ float vbuf[CH];            // 16 KB sorted values
  __shared__ unsigned char gbuf[CH];    // 4 KB gid per sorted slot
  __shared__ unsigned wcnt[4][NG];      // running counters (seeded, non-atomic)
  __shared__ unsigned bias[NG];         // global_dest - local_base per group
  __shared__ unsigned wsum[4];          // cross-wave scan scratch
  const int t    = threadIdx.x;
  const int lane = t & 63;
  const int w    = t >> 6;
  const int b = blockIdx.x / NC;
  const int c = blockIdx.x % NC;
  const size_t base = (size_t)b*NN + (size_t)c*CH;
  const size_t cb   = (size_t)b*NC + c;

  // phase 0: load per-wave counts + absolute offset; shfl-scan local bases
  {
    unsigned long long x = wcnt16[cb*NG + t];   // thread t == group id
    unsigned offt = off[cb*NG + t];
    unsigned lo = (unsigned)x, hi = (unsigned)(x >> 32);
    unsigned w0 = lo & 0xFFFFu, w1 = lo >> 16, w2 = hi & 0xFFFFu, w3 = hi >> 16;
    unsigned tot = w0 + w1 + w2 + w3;

    unsigned v = tot;                           // wave-inclusive scan over lanes
#pragma unroll
    for (int d = 1; d < 64; d <<= 1){
      unsigned y = __shfl_up(v, d, 64);
      if (lane >= d) v += y;
    }
    if (lane == 63) wsum[w] = v;
    __syncthreads();
    unsigned pre = 0;
#pragma unroll
    for (int k = 0; k < 3; k++) if (k < w) pre += wsum[k];
    unsigned lb = pre + v - tot;                // exclusive prefix over groups < t
    wcnt[0][t] = lb;
    wcnt[1][t] = lb + w0;
    wcnt[2][t] = lb + w0 + w1;
    wcnt[3][t] = lb + w0 + w1 + w2;
    bias[t] = offt - lb;
  }
  __syncthreads();

  // phase 1: stable scatter into LDS (per wave, element order)
  {
    const unsigned long long below = (lane == 0) ? 0ull : ((1ull << lane) - 1ull);
    const float*    psrc = pr    + base        + (size_t)w*SC;
    const unsigned* gsrc = gid32 + (base >> 2) + (size_t)w*(SC/4);
    const int shft = (lane & 3) * 8;

    float pv[16]; unsigned pk[16];              // batch all loads upfront
#pragma unroll
    for (int s = 0; s < 16; s++){
      pv[s] = psrc[s*64 + lane];
      pk[s] = gsrc[s*16 + (lane >> 2)];         // 4 lanes share one word
    }
#pragma unroll
    for (int s = 0; s < 16; s++){
      int g = (int)((pk[s] >> shft) & 255u);
      unsigned long long mask = ~0ull;
#pragma unroll
      for (int bit = 0; bit < 8; bit++){
        int bv = (g >> bit) & 1;
        unsigned long long bal = __ballot(bv);
        mask &= bv ? bal : ~bal;
      }
      int rank = __popcll(mask & below);
      unsigned old = wcnt[w][g];                // all lanes read pre-update value
      if (rank == 0) wcnt[w][g] = old + (unsigned)__popcll(mask);
      vbuf[old + (unsigned)rank] = pv[s];
      gbuf[old + (unsigned)rank] = (unsigned char)g;
    }
  }
  __syncthreads();

  // phase 2: coalesced flush (consecutive p -> consecutive dest within runs)
  {
    float* dst = sorted + (size_t)b*NN;
    const unsigned* gbuf32 = (const unsigned*)gbuf;
#pragma unroll
    for (int k = 0; k < CH/256; k++){      // 16 iters
      int p = k*256 + t;
      unsigned packed = gbuf32[p >> 2];    // broadcast within 4 threads
      unsigned g = (packed >> ((p & 3) * 8)) & 255u;
      dst[bias[g] + (unsigned)p] = vbuf[p];
    }
  }
}

// ---- Pass 4: one LANE per (batch,group); float4 loads, 8-deep register
//      pipeline. Scalar head to 16B alignment + scalar tail keep the fp32 add
//      chain in exact element order (bit-exact). ----
__global__ __launch_bounds__(32) void k_sum(const float* __restrict__ sorted,
                                            const unsigned* __restrict__ grpbase,
                                            const unsigned* __restrict__ grplen,
                                            float* __restrict__ gsum,
                                            float* __restrict__ gmn,
                                            float* __restrict__ gmx){
  const int lane = threadIdx.x;                  // 0..31
  const int b = blockIdx.x >> 3;                 // 8 blocks per batch
  const int g = ((blockIdx.x & 7) << 5) + lane;  // one group per lane

  const unsigned base = grpbase[b*NG + g];
  const unsigned len  = grplen [b*NG + g];
  const float* sp = sorted + (size_t)b*NN + base;

  float s = 0.0f, mn = INFINITY, mx = -INFINITY;

  // scalar head to 16B alignment (element order preserved)
  unsigned head = (4u - ((unsigned)(((size_t)sp) >> 2) & 3u)) & 3u;
  if (head > len) head = len;
  for (unsigned i = 0; i < head; i++){
    float v = sp[i];
    s = __fadd_rn(s, v); mn = fminf(mn, v); mx = fmaxf(mx, v);
  }
  const float4* f4 = (const float4*)(sp + head);
  const unsigned rem   = len - head;
  const unsigned nfull = rem >> 4;               // 16-elem batches (4 x float4)

  float4 b0[4], b1[4], b2[4], b3[4], b4[4], b5[4], b6[4], b7[4];
#define LOADV(D, K) { D[0]=f4[(K)*4+0]; D[1]=f4[(K)*4+1]; D[2]=f4[(K)*4+2]; D[3]=f4[(K)*4+3]; }
#define CONS1(V)    { s=__fadd_rn(s,(V)); mn=fminf(mn,(V)); mx=fmaxf(mx,(V)); }
#define CONSV(D)    { _Pragma("unroll") for (int j = 0; j < 4; j++){ float4 q = D[j]; \
                      CONS1(q.x) CONS1(q.y) CONS1(q.z) CONS1(q.w) } }

  if (nfull > 0) LOADV(b0, 0)
  if (nfull > 1) LOADV(b1, 1)
  if (nfull > 2) LOADV(b2, 2)
  if (nfull > 3) LOADV(b3, 3)
  if (nfull > 4) LOADV(b4, 4)
  if (nfull > 5) LOADV(b5, 5)
  if (nfull > 6) LOADV(b6, 6)
  if (nfull > 7) LOADV(b7, 7)
  unsigned k = 0;
  for (; k + 8 <= nfull; k += 8){
    CONSV(b0) if (k +  8 < nfull) LOADV(b0, k +  8)
    CONSV(b1) if (k +  9 < nfull) LOADV(b1, k +  9)
    CONSV(b2) if (k + 10 < nfull) LOADV(b2, k + 10)
    CONSV(b3) if (k + 11 < nfull) LOADV(b3, k + 11)
    CONSV(b4) if (k + 12 < nfull) LOADV(b4, k + 12)
    CONSV(b5) if (k + 13 < nfull) LOADV(b5, k + 13)
    CONSV(b6) if (k + 14 < nfull) LOADV(b6, k + 14)
    CONSV(b7) if (k + 15 < nfull) LOADV(b7, k + 15)
  }
  {
    unsigned r = nfull - k;        // 0..7 remaining full batches in b0..b6
    if (r > 0) CONSV(b0)
    if (r > 1) CONSV(b1)
    if (r > 2) CONSV(b2)
    if (r > 3) CONSV(b3)
    if (r > 4) CONSV(b4)
    if (r > 5) CONSV(b5)
    if (r > 6) CONSV(b6)
  }
  for (unsigned i = head + (nfull << 4); i < len; i++){
    float v = sp[i];
    s = __fadd_rn(s, v); mn = fminf(mn, v); mx = fmaxf(mx, v);
  }
#undef LOADV
#undef CONS1
#undef CONSV

  gsum[b*NG + g] = s;
  gmn [b*NG + g] = mn;
  gmx [b*NG + g] = mx;
}

// ---- Pass 5: per-batch group pipeline (blend, stable rank, f0/f1, no_scale) ----
// params layout: SoA, params[(b*4 + comp)*NG + g]
__global__ __launch_bounds__(256) void k_pipeline(const float* __restrict__ gsum,
                                                  const float* __restrict__ gmn,
                                                  const float* __restrict__ gmx,
                                                  const float* __restrict__ inp_means,
                                                  const float* __restrict__ Wv,
                                                  float* __restrict__ params){
  const int b = blockIdx.x;
  const int g = threadIdx.x;
  __shared__ float vm[NG];
  __shared__ float vs[NG];

  const float s   = gsum[b*NG + g];   // empty group: len==0 -> s==0 (matches where(vany,...))
  const float mnf = gmn [b*NG + g];
  const float mxf = gmx [b*NG + g];
  const float W0 = Wv[0], W1 = Wv[1];
  float mean = __fdiv_rn(__fadd_rn(__fmul_rn(inp_means[b*NG + g], W0),
                                   __fmul_rn(s, W1)),
                         __fadd_rn(W0, W1));
  vm[g] = mean;
  __syncthreads();

  // stable rank == position after stable argsort
  int r = 0;
  for (int j = 0; j < NG; j++){
    float x = vm[j];
    r += (x < mean) || (x == mean && j < g);
  }
  vs[r] = mean;
  __syncthreads();

  float c0 = (r == 0)    ? vs[0]                     : vs[r-1];
  float c1 = vs[r];
  float c2 = (r == NG-1) ? __fmul_rn(vs[NG-1], 2.0f) : vs[r+1];
  float f0 = __fdiv_rn(__fadd_rn(c0, c1), 1.999f);
  float f1 = __fdiv_rn(__fadd_rn(c1, c2), 2.001f);

  bool ns = (mnf == mxf);
  params[(b*4 + 0)*NG + g] = ns ? 0.0f : mnf;                  // vmin_use
  params[(b*4 + 1)*NG + g] = ns ? 1.0f : __fsub_rn(mxf, mnf);  // range_use
  params[(b*4 + 2)*NG + g] = ns ? 1.0f : __fsub_rn(f1, f0);    // (f1-f0)_use
  params[(b*4 + 3)*NG + g] = ns ? 0.0f : f0;                   // f0_use
}

// ---- Pass 6: per-element apply, fp32 replicating reference op order ----
static __device__ __forceinline__ float apply_one(float p, unsigned g,
                                                  const float* __restrict__ sp0,
                                                  const float* __restrict__ sp1,
                                                  const float* __restrict__ sp2,
                                                  const float* __restrict__ sp3){
  float t1  = __fsub_rn(p, sp0[g]);
  float t3  = __fdiv_rn(t1, sp1[g]);
  float t5  = __fmul_rn(t3, sp2[g]);
  float tmp = __fadd_rn(t5, sp3[g]);
  bool bad = __builtin_isnan(tmp) || (tmp == 0.0f);
  float s = __fdiv_rn(p, bad ? 1.0f : tmp);
  bool bad2 = bad || __builtin_isnan(s) || __builtin_isinf(s);
  float sc = bad2 ? 0.0f : s;
  return __fmul_rn(p, sc);
}

__global__ __launch_bounds__(256) void k_apply(const float* __restrict__ pr,
                                               const unsigned* __restrict__ gid32,
                                               const float* __restrict__ params,
                                               float* __restrict__ out){
  __shared__ float sp0[NG], sp1[NG], sp2[NG], sp3[NG];
  const int t = threadIdx.x;
  const int b = blockIdx.x / CD;
  const int c = blockIdx.x % CD;

  sp0[t] = params[(b*4 + 0)*NG + t];
  sp1[t] = params[(b*4 + 1)*NG + t];
  sp2[t] = params[(b*4 + 2)*NG + t];
  sp3[t] = params[(b*4 + 3)*NG + t];
  __syncthreads();

  const size_t base = (size_t)b*NN + (size_t)c*ELD;
  const float4* p4 = (const float4*)(pr + base);
  float4* o4 = (float4*)(out + base);

#pragma unroll
  for (int i = 0; i < ELD/1024; i++){
    float4 p = p4[i*256 + t];
    unsigned pk = gid32[(base >> 2) + i*256 + t];
    float4 r;
    r.x = apply_one(p.x,  pk        & 255u, sp0, sp1, sp2, sp3);
    r.y = apply_one(p.y, (pk >>  8) & 255u, sp0, sp1, sp2, sp3);
    r.z = apply_one(p.z, (pk >> 16) & 255u, sp0, sp1, sp2, sp3);
    r.w = apply_one(p.w,  pk >> 24,         sp0, sp1, sp2, sp3);
    o4[i*256 + t] = r;
  }
}

extern "C" void kernel_launch(void* const* d_in, const int* in_sizes, int n_in,
                              void* d_out, int out_size, void* d_ws, size_t ws_size,
                              hipStream_t stream){
  const float* pr        = (const float*)d_in[0];
  const float* inp_means = (const float*)d_in[1];
  const int*   vr        = (const int*)d_in[2];
  const float* W         = (const float*)d_in[3];
  float* out = (float*)d_out;

  char* ws = (char*)d_ws;
  size_t o = 0;
  unsigned long long* wcnt16 = (unsigned long long*)(ws + o); o += (size_t)NB*NC*NG*8; // 4 MB
  unsigned* off     = (unsigned*)(ws + o); o += (size_t)NB*NC*NG*4;  // 2 MB
  unsigned* gid32   = (unsigned*)(ws + o); o += (size_t)NB*NN;       // 8 MB packed u8 gids
  unsigned* grpbase = (unsigned*)(ws + o); o += (size_t)NB*NG*4;     // 32 KB
  unsigned* grplen  = (unsigned*)(ws + o); o += (size_t)NB*NG*4;
  float*    gsum    = (float*)   (ws + o); o += (size_t)NB*NG*4;
  float*    gmn     = (float*)   (ws + o); o += (size_t)NB*NG*4;
  float*    gmx     = (float*)   (ws + o); o += (size_t)NB*NG*4;
  float*    params  = (float*)   (ws + o); o += (size_t)NB*NG*16;    // 128 KB (SoA)
  // sorted values live in d_out (fully overwritten by k_apply afterwards)
  float* sorted = out;

  k_count   <<<NB*NC, 256, 0, stream>>>(vr, wcnt16, gid32);
  k_offsets <<<NB,     NG, 0, stream>>>(wcnt16, off, grpbase, grplen);
  k_scatter <<<NB*NC, 256, 0, stream>>>(pr, gid32, off, wcnt16, sorted);
  k_sum     <<<NB*8,   32, 0, stream>>>(sorted, grpbase, grplen, gsum, gmn, gmx);
  k_pipeline<<<NB,     NG, 0, stream>>>(gsum, gmn, gmx, inp_means, W, params);
  k_apply   <<<NB*CD, 256, 0, stream>>>(pr, gid32, params, out);
}